// Round 6
// baseline (816.967 us; speedup 1.0000x reference)
//
#include <hip/hip_runtime.h>

// ================= degree =================

__global__ void k_count(const int* __restrict__ dst, int* __restrict__ cnt, int e) {
    int i = blockIdx.x * blockDim.x + threadIdx.x;
    if (i < e) atomicAdd(&cnt[dst[i]], 1);
}

// ---- 3-phase scan over cnt -> rowptr/cursor (+ dinv fused) ----
#define SCP 1024

__global__ void k_scan_a(const int* __restrict__ cnt, int* __restrict__ part, int n) {
    int p = blockIdx.x * blockDim.x + threadIdx.x;
    if (p >= SCP) return;
    int chunk = (n + SCP - 1) / SCP;
    int b = p * chunk, e = min(b + chunk, n), s = 0;
    for (int i = b; i < e; ++i) s += cnt[i];
    part[p] = s;
}

__global__ void k_scan_b(int* __restrict__ part) {   // 1 block, 1024 threads
    __shared__ int sm[SCP];
    int t = threadIdx.x;
    sm[t] = part[t];
    __syncthreads();
    for (int off = 1; off < SCP; off <<= 1) {
        int v = (t >= off) ? sm[t - off] : 0;
        __syncthreads();
        sm[t] += v;
        __syncthreads();
    }
    part[t] = t ? sm[t - 1] : 0;   // exclusive
}

__global__ void k_scan_c(const int* __restrict__ cnt, const int* __restrict__ part,
                         int* __restrict__ rowptr, int* __restrict__ cursor,
                         float* __restrict__ dinv, int n) {
    int p = blockIdx.x * blockDim.x + threadIdx.x;
    if (p >= SCP) return;
    int chunk = (n + SCP - 1) / SCP;
    int b = p * chunk, e = min(b + chunk, n);
    int run = part[p];
    for (int i = b; i < e; ++i) {
        rowptr[i] = run;
        cursor[i] = run;
        dinv[i] = rsqrtf((float)(cnt[i] + 1));   // +1 self-loop
        run += cnt[i];
    }
    if (p == SCP - 1) rowptr[n] = run;
}

__global__ void k_fill(const int* __restrict__ src, const int* __restrict__ dstv,
                       int* __restrict__ cursor, int* __restrict__ csr_src, int e) {
    int i = blockIdx.x * blockDim.x + threadIdx.x;
    if (i < e) {
        int pos = atomicAdd(&cursor[dstv[i]], 1);
        __builtin_nontemporal_store(src[i], &csr_src[pos]);
    }
}

// ================= GEMM: C[row] = dinv[row] * (A[row] @ W)  =================
// LDS-tiled register-blocked fp32 GEMM, register-prefetch double buffering.
// BM=128 rows/block, BK=32 k-slab. 256 threads as 16x16; thread tile 8 x TN.

template<int COUT>
__global__ __launch_bounds__(256) void k_gemm(const float* __restrict__ A,
                                              const float* __restrict__ W,
                                              const float* __restrict__ dinv,
                                              float* __restrict__ C, int n) {
    const int BM = 128, BK = 32;
    const int TN = COUT / 16;                 // 8 (COUT=128) or 4 (COUT=64)
    const int WPT = BK * COUT / 4 / 256;      // W float4s per thread: 4 or 2
    __shared__ float sA[BK][BM + 4];
    __shared__ float sW[BK][COUT + 4];

    int tid = threadIdx.x;
    int row0 = blockIdx.x * BM;
    int tr = tid & 15, tc = tid >> 4;
    int r0 = tr * 8, c0 = tc * TN;

    float4 pa[4];
    float4 pw[WPT];

    auto load_slab = [&](int slab) {
#pragma unroll
        for (int t = 0; t < 4; ++t) {
            int f = tid + t * 256;            // 1024 float4s
            int row = f >> 3, k4 = f & 7;
            int gr = min(row0 + row, n - 1);
            pa[t] = *reinterpret_cast<const float4*>(A + (long)gr * 128 + slab * 32 + k4 * 4);
        }
#pragma unroll
        for (int t = 0; t < WPT; ++t) {
            int f = tid + t * 256;
            int k = f / (COUT / 4), c4 = (f % (COUT / 4)) * 4;
            pw[t] = *reinterpret_cast<const float4*>(W + (long)(slab * 32 + k) * COUT + c4);
        }
    };
    auto store_slab = [&]() {
#pragma unroll
        for (int t = 0; t < 4; ++t) {
            int f = tid + t * 256;
            int row = f >> 3, k4 = f & 7;
            sA[k4 * 4 + 0][row] = pa[t].x;
            sA[k4 * 4 + 1][row] = pa[t].y;
            sA[k4 * 4 + 2][row] = pa[t].z;
            sA[k4 * 4 + 3][row] = pa[t].w;
        }
#pragma unroll
        for (int t = 0; t < WPT; ++t) {
            int f = tid + t * 256;
            int k = f / (COUT / 4), c4 = (f % (COUT / 4)) * 4;
            *reinterpret_cast<float4*>(&sW[k][c4]) = pw[t];
        }
    };

    float acc[8][TN];
#pragma unroll
    for (int i = 0; i < 8; ++i)
#pragma unroll
        for (int j = 0; j < TN; ++j) acc[i][j] = 0.f;

    load_slab(0);
    store_slab();
    __syncthreads();

    for (int slab = 0; slab < 4; ++slab) {
        if (slab < 3) load_slab(slab + 1);    // prefetch next slab into registers

#pragma unroll
        for (int k = 0; k < BK; ++k) {
            float a[8], w[TN];
            *reinterpret_cast<float4*>(&a[0]) = *reinterpret_cast<const float4*>(&sA[k][r0]);
            *reinterpret_cast<float4*>(&a[4]) = *reinterpret_cast<const float4*>(&sA[k][r0 + 4]);
#pragma unroll
            for (int j = 0; j < TN; j += 4)
                *reinterpret_cast<float4*>(&w[j]) = *reinterpret_cast<const float4*>(&sW[k][c0 + j]);
#pragma unroll
            for (int i = 0; i < 8; ++i)
#pragma unroll
                for (int j = 0; j < TN; ++j)
                    acc[i][j] = fmaf(a[i], w[j], acc[i][j]);
        }
        __syncthreads();
        if (slab < 3) {
            store_slab();
            __syncthreads();
        }
    }

#pragma unroll
    for (int i = 0; i < 8; ++i) {
        int row = row0 + r0 + i;
        if (row < n) {
            float dv = dinv[row];
#pragma unroll
            for (int j = 0; j < TN; ++j) acc[i][j] *= dv;
#pragma unroll
            for (int j = 0; j < TN; j += 4)
                *reinterpret_cast<float4*>(C + (long)row * COUT + c0 + j) =
                    *reinterpret_cast<float4*>(&acc[i][j]);
        }
    }
}

// ================= pull aggregation =================
// out[d] = act( dinv[d] * ( ht[d] + sum_{s in N(d)} ht[s] ) + bias ),  ht pre-scaled by dinv.

template<int C, bool RELU>
__global__ void k_gather(const int* __restrict__ rowptr, const int* __restrict__ csr_src,
                         const float* __restrict__ dinv, const float* __restrict__ h,
                         const float* __restrict__ bias, float* __restrict__ out, int n) {
    const int TPN = C / 4;
    int t = blockIdx.x * blockDim.x + threadIdx.x;
    int node = t / TPN;
    if (node >= n) return;
    int c = (t % TPN) * 4;

    const float4* h4 = reinterpret_cast<const float4*>(h);
    float4 acc = h4[((long)node * C + c) >> 2];   // self-loop term (already dinv-scaled)

    int beg = rowptr[node], end = rowptr[node + 1];
    int e = beg;
    // 8-deep MLP: 8 independent row loads in flight
    for (; e + 8 <= end; e += 8) {
        int s[8];
#pragma unroll
        for (int q = 0; q < 8; ++q) s[q] = csr_src[e + q];
        float4 u[8];
#pragma unroll
        for (int q = 0; q < 8; ++q) u[q] = h4[((long)s[q] * C + c) >> 2];
        float sx0 = (u[0].x + u[1].x) + (u[2].x + u[3].x);
        float sx1 = (u[4].x + u[5].x) + (u[6].x + u[7].x);
        float sy0 = (u[0].y + u[1].y) + (u[2].y + u[3].y);
        float sy1 = (u[4].y + u[5].y) + (u[6].y + u[7].y);
        float sz0 = (u[0].z + u[1].z) + (u[2].z + u[3].z);
        float sz1 = (u[4].z + u[5].z) + (u[6].z + u[7].z);
        float sw0 = (u[0].w + u[1].w) + (u[2].w + u[3].w);
        float sw1 = (u[4].w + u[5].w) + (u[6].w + u[7].w);
        acc.x += sx0 + sx1; acc.y += sy0 + sy1;
        acc.z += sz0 + sz1; acc.w += sw0 + sw1;
    }
    for (; e < end; ++e) {
        int s = csr_src[e];
        float4 u = h4[((long)s * C + c) >> 2];
        acc.x += u.x; acc.y += u.y; acc.z += u.z; acc.w += u.w;
    }
    float dd = dinv[node];
    float4 b4 = *reinterpret_cast<const float4*>(bias + c);
    acc.x = fmaf(acc.x, dd, b4.x);
    acc.y = fmaf(acc.y, dd, b4.y);
    acc.z = fmaf(acc.z, dd, b4.z);
    acc.w = fmaf(acc.w, dd, b4.w);
    if (RELU) {
        acc.x = fmaxf(acc.x, 0.f); acc.y = fmaxf(acc.y, 0.f);
        acc.z = fmaxf(acc.z, 0.f); acc.w = fmaxf(acc.w, 0.f);
    }
    reinterpret_cast<float4*>(out)[((long)node * C + c) >> 2] = acc;
}

// ================= decode =================

__global__ void k_decode(const int* __restrict__ ia, const int* __restrict__ ib,
                         const float* __restrict__ z, float* __restrict__ out, int m) {
    int t = blockIdx.x * blockDim.x + threadIdx.x;
    int k = t / 16;
    if (k >= m) return;
    int c = (t & 15) * 4;
    int a = ia[k], b = ib[k];
    float4 va = *reinterpret_cast<const float4*>(z + (long)a * 64 + c);
    float4 vb = *reinterpret_cast<const float4*>(z + (long)b * 64 + c);
    float dot = va.x * vb.x + va.y * vb.y + va.z * vb.z + va.w * vb.w;
    dot += __shfl_xor(dot, 8);
    dot += __shfl_xor(dot, 4);
    dot += __shfl_xor(dot, 2);
    dot += __shfl_xor(dot, 1);
    if ((t & 15) == 0) out[k] = dot;
}

// ================= launcher =================

extern "C" void kernel_launch(void* const* d_in, const int* in_sizes, int n_in,
                              void* d_out, int out_size, void* d_ws, size_t ws_size,
                              hipStream_t stream) {
    const float* x  = (const float*)d_in[0];
    const int*   ei = (const int*)d_in[1];
    const int*   el = (const int*)d_in[2];
    const float* W1 = (const float*)d_in[3];
    const float* b1 = (const float*)d_in[4];
    const float* W2 = (const float*)d_in[5];
    const float* b2 = (const float*)d_in[6];
    float* out = (float*)d_out;

    const int N = in_sizes[0] / 128;
    const int E = in_sizes[1] / 2;
    const int L = out_size;

    const int* src = ei;
    const int* dst = ei + E;
    const int* la  = el;
    const int* lb  = el + L;

    // ---- workspace layout ----
    float* bufA = (float*)d_ws;                     // N*128
    float* bufB = bufA + (long)N * 128;             // N*128
    int*   csr_src = (int*)(bufB + (long)N * 128);  // E
    int*   cnt     = csr_src + E;                   // N
    int*   rowptr  = cnt + N;                       // N+1
    int*   cursor  = rowptr + N + 1;                // N
    float* dinv    = (float*)(cursor + N);          // N
    int*   part    = (int*)(dinv + N);              // SCP
    float* z    = bufA;                             // N*64 (reuse)
    float* zout = bufA + (long)N * 64;              // N*64 (reuse)

    auto cdiv = [](long a, long b) { return (int)((a + b - 1) / b); };

    // ---- CSR build + normalization ----
    hipMemsetAsync(cnt, 0, (size_t)N * sizeof(int), stream);
    k_count <<<cdiv(E, 256), 256, 0, stream>>>(dst, cnt, E);
    k_scan_a<<<SCP / 256, 256, 0, stream>>>(cnt, part, N);
    k_scan_b<<<1, SCP, 0, stream>>>(part);
    k_scan_c<<<SCP / 256, 256, 0, stream>>>(cnt, part, rowptr, cursor, dinv, N);
    k_fill  <<<cdiv(E, 256), 256, 0, stream>>>(src, dst, cursor, csr_src, E);

    // ---- layer 1: h = relu(agg(x @ W1) + b1) ----
    k_gemm<128><<<cdiv(N, 128), 256, 0, stream>>>(x, W1, dinv, bufA, N);
    k_gather<128, true><<<cdiv((long)N * 32, 256), 256, 0, stream>>>(
        rowptr, csr_src, dinv, bufA, b1, bufB, N);

    // ---- layer 2: z = agg(h @ W2) + b2 ----
    k_gemm<64><<<cdiv(N, 128), 256, 0, stream>>>(bufB, W2, dinv, z, N);
    k_gather<64, false><<<cdiv((long)N * 16, 256), 256, 0, stream>>>(
        rowptr, csr_src, dinv, z, b2, zout, N);

    // ---- decode ----
    k_decode<<<cdiv((long)L * 16, 256), 256, 0, stream>>>(la, lb, zout, out, L);
}

// Round 7
// 517.240 us; speedup vs baseline: 1.5795x; 1.5795x over previous
//
#include <hip/hip_runtime.h>

// ================= degree =================

__global__ void k_count(const int* __restrict__ dst, int* __restrict__ cnt, int e) {
    int i = blockIdx.x * blockDim.x + threadIdx.x;
    if (i < e) atomicAdd(&cnt[dst[i]], 1);
}

// ---- 3-phase scan over cnt -> rowptr/cursor (+ dinv fused) ----
#define SCP 1024

__global__ void k_scan_a(const int* __restrict__ cnt, int* __restrict__ part, int n) {
    int p = blockIdx.x * blockDim.x + threadIdx.x;
    if (p >= SCP) return;
    int chunk = (n + SCP - 1) / SCP;
    int b = p * chunk, e = min(b + chunk, n), s = 0;
    for (int i = b; i < e; ++i) s += cnt[i];
    part[p] = s;
}

__global__ void k_scan_b(int* __restrict__ part) {   // 1 block, 1024 threads
    __shared__ int sm[SCP];
    int t = threadIdx.x;
    sm[t] = part[t];
    __syncthreads();
    for (int off = 1; off < SCP; off <<= 1) {
        int v = (t >= off) ? sm[t - off] : 0;
        __syncthreads();
        sm[t] += v;
        __syncthreads();
    }
    part[t] = t ? sm[t - 1] : 0;   // exclusive
}

__global__ void k_scan_c(const int* __restrict__ cnt, const int* __restrict__ part,
                         int* __restrict__ rowptr, int* __restrict__ cursor,
                         float* __restrict__ dinv, int n) {
    int p = blockIdx.x * blockDim.x + threadIdx.x;
    if (p >= SCP) return;
    int chunk = (n + SCP - 1) / SCP;
    int b = p * chunk, e = min(b + chunk, n);
    int run = part[p];
    for (int i = b; i < e; ++i) {
        rowptr[i] = run;
        cursor[i] = run;
        dinv[i] = rsqrtf((float)(cnt[i] + 1));   // +1 self-loop
        run += cnt[i];
    }
    if (p == SCP - 1) rowptr[n] = run;
}

// ---- XCD-partitioned CSR fill ----
// Round-robin dispatch maps blockIdx%8 -> XCD. Block (r,g) scans chunk g of the
// edge list and handles only edges whose dst falls in node-range r. All writes
// to cursor[d] and csr_src[rowptr[d]..] for range r then come from one XCD ->
// lines stay in that XCD's L2 and flush once (vs ~16 bounced flushes).
__global__ void k_fillx(const int* __restrict__ src, const int* __restrict__ dstv,
                        int* __restrict__ cursor, int* __restrict__ csr_src,
                        int e, float scale) {
    int r = blockIdx.x & 7;
    int g = blockIdx.x >> 3;
    int G = gridDim.x >> 3;
    int chunk = (e + G - 1) / G;
    int beg = g * chunk, end = min(beg + chunk, e);
    for (int i = beg + threadIdx.x; i < end; i += blockDim.x) {
        int d = dstv[i];
        if ((int)((float)d * scale) == r) {
            int pos = atomicAdd(&cursor[d], 1);
            __builtin_nontemporal_store(src[i], &csr_src[pos]);
        }
    }
}

// ================= GEMM: C[row] = dinv[row] * (A[row] @ W)  =================
// LDS-tiled register-blocked fp32 GEMM (single-buffered; R3-verified).
// BM=128 rows/block, BK=32 k-slab. 256 threads as 16x16; thread tile 8 x TN.

template<int COUT>
__global__ __launch_bounds__(256) void k_gemm(const float* __restrict__ A,
                                              const float* __restrict__ W,
                                              const float* __restrict__ dinv,
                                              float* __restrict__ C, int n) {
    const int BM = 128, BK = 32;
    const int TN = COUT / 16;                 // 8 (COUT=128) or 4 (COUT=64)
    __shared__ float sA[BK][BM + 4];
    __shared__ float sW[BK][COUT + 4];

    int tid = threadIdx.x;
    int row0 = blockIdx.x * BM;
    int tr = tid & 15, tc = tid >> 4;
    int r0 = tr * 8, c0 = tc * TN;

    float acc[8][TN];
#pragma unroll
    for (int i = 0; i < 8; ++i)
#pragma unroll
        for (int j = 0; j < TN; ++j) acc[i][j] = 0.f;

    for (int slab = 0; slab < 4; ++slab) {
#pragma unroll
        for (int t = 0; t < 4; ++t) {
            int f = tid + t * 256;            // 1024 float4s
            int row = f >> 3, k4 = f & 7;
            int gr = min(row0 + row, n - 1);
            float4 v = *reinterpret_cast<const float4*>(A + (long)gr * 128 + slab * 32 + k4 * 4);
            sA[k4 * 4 + 0][row] = v.x;
            sA[k4 * 4 + 1][row] = v.y;
            sA[k4 * 4 + 2][row] = v.z;
            sA[k4 * 4 + 3][row] = v.w;
        }
        const int WF4 = BK * COUT / 4;
        for (int f = tid; f < WF4; f += 256) {
            int k = f / (COUT / 4), c4 = (f % (COUT / 4)) * 4;
            float4 v = *reinterpret_cast<const float4*>(W + (long)(slab * 32 + k) * COUT + c4);
            *reinterpret_cast<float4*>(&sW[k][c4]) = v;
        }
        __syncthreads();

#pragma unroll
        for (int k = 0; k < BK; ++k) {
            float a[8], w[TN];
            *reinterpret_cast<float4*>(&a[0]) = *reinterpret_cast<const float4*>(&sA[k][r0]);
            *reinterpret_cast<float4*>(&a[4]) = *reinterpret_cast<const float4*>(&sA[k][r0 + 4]);
#pragma unroll
            for (int j = 0; j < TN; j += 4)
                *reinterpret_cast<float4*>(&w[j]) = *reinterpret_cast<const float4*>(&sW[k][c0 + j]);
#pragma unroll
            for (int i = 0; i < 8; ++i)
#pragma unroll
                for (int j = 0; j < TN; ++j)
                    acc[i][j] = fmaf(a[i], w[j], acc[i][j]);
        }
        __syncthreads();
    }

#pragma unroll
    for (int i = 0; i < 8; ++i) {
        int row = row0 + r0 + i;
        if (row < n) {
            float dv = dinv[row];
#pragma unroll
            for (int j = 0; j < TN; ++j) acc[i][j] *= dv;
#pragma unroll
            for (int j = 0; j < TN; j += 4)
                *reinterpret_cast<float4*>(C + (long)row * COUT + c0 + j) =
                    *reinterpret_cast<float4*>(&acc[i][j]);
        }
    }
}

// ================= pull aggregation =================
// out[d] = act( dinv[d] * ( ht[d] + sum_{s in N(d)} ht[s] ) + bias ),  ht pre-scaled by dinv.

template<int C, bool RELU>
__global__ void k_gather(const int* __restrict__ rowptr, const int* __restrict__ csr_src,
                         const float* __restrict__ dinv, const float* __restrict__ h,
                         const float* __restrict__ bias, float* __restrict__ out, int n) {
    const int TPN = C / 4;
    int t = blockIdx.x * blockDim.x + threadIdx.x;
    int node = t / TPN;
    if (node >= n) return;
    int c = (t % TPN) * 4;

    const float4* h4 = reinterpret_cast<const float4*>(h);
    float4 acc = h4[((long)node * C + c) >> 2];   // self-loop term (already dinv-scaled)

    int beg = rowptr[node], end = rowptr[node + 1];
    int e = beg;
    // 8-deep MLP: 8 independent row loads in flight
    for (; e + 8 <= end; e += 8) {
        int s[8];
#pragma unroll
        for (int q = 0; q < 8; ++q) s[q] = csr_src[e + q];
        float4 u[8];
#pragma unroll
        for (int q = 0; q < 8; ++q) u[q] = h4[((long)s[q] * C + c) >> 2];
        float sx0 = (u[0].x + u[1].x) + (u[2].x + u[3].x);
        float sx1 = (u[4].x + u[5].x) + (u[6].x + u[7].x);
        float sy0 = (u[0].y + u[1].y) + (u[2].y + u[3].y);
        float sy1 = (u[4].y + u[5].y) + (u[6].y + u[7].y);
        float sz0 = (u[0].z + u[1].z) + (u[2].z + u[3].z);
        float sz1 = (u[4].z + u[5].z) + (u[6].z + u[7].z);
        float sw0 = (u[0].w + u[1].w) + (u[2].w + u[3].w);
        float sw1 = (u[4].w + u[5].w) + (u[6].w + u[7].w);
        acc.x += sx0 + sx1; acc.y += sy0 + sy1;
        acc.z += sz0 + sz1; acc.w += sw0 + sw1;
    }
    for (; e < end; ++e) {
        int s = csr_src[e];
        float4 u = h4[((long)s * C + c) >> 2];
        acc.x += u.x; acc.y += u.y; acc.z += u.z; acc.w += u.w;
    }
    float dd = dinv[node];
    float4 b4 = *reinterpret_cast<const float4*>(bias + c);
    acc.x = fmaf(acc.x, dd, b4.x);
    acc.y = fmaf(acc.y, dd, b4.y);
    acc.z = fmaf(acc.z, dd, b4.z);
    acc.w = fmaf(acc.w, dd, b4.w);
    if (RELU) {
        acc.x = fmaxf(acc.x, 0.f); acc.y = fmaxf(acc.y, 0.f);
        acc.z = fmaxf(acc.z, 0.f); acc.w = fmaxf(acc.w, 0.f);
    }
    reinterpret_cast<float4*>(out)[((long)node * C + c) >> 2] = acc;
}

// ================= decode =================

__global__ void k_decode(const int* __restrict__ ia, const int* __restrict__ ib,
                         const float* __restrict__ z, float* __restrict__ out, int m) {
    int t = blockIdx.x * blockDim.x + threadIdx.x;
    int k = t / 16;
    if (k >= m) return;
    int c = (t & 15) * 4;
    int a = ia[k], b = ib[k];
    float4 va = *reinterpret_cast<const float4*>(z + (long)a * 64 + c);
    float4 vb = *reinterpret_cast<const float4*>(z + (long)b * 64 + c);
    float dot = va.x * vb.x + va.y * vb.y + va.z * vb.z + va.w * vb.w;
    dot += __shfl_xor(dot, 8);
    dot += __shfl_xor(dot, 4);
    dot += __shfl_xor(dot, 2);
    dot += __shfl_xor(dot, 1);
    if ((t & 15) == 0) out[k] = dot;
}

// ================= launcher =================

extern "C" void kernel_launch(void* const* d_in, const int* in_sizes, int n_in,
                              void* d_out, int out_size, void* d_ws, size_t ws_size,
                              hipStream_t stream) {
    const float* x  = (const float*)d_in[0];
    const int*   ei = (const int*)d_in[1];
    const int*   el = (const int*)d_in[2];
    const float* W1 = (const float*)d_in[3];
    const float* b1 = (const float*)d_in[4];
    const float* W2 = (const float*)d_in[5];
    const float* b2 = (const float*)d_in[6];
    float* out = (float*)d_out;

    const int N = in_sizes[0] / 128;
    const int E = in_sizes[1] / 2;
    const int L = out_size;

    const int* src = ei;
    const int* dst = ei + E;
    const int* la  = el;
    const int* lb  = el + L;

    // ---- workspace layout ----
    float* bufA = (float*)d_ws;                     // N*128
    float* bufB = bufA + (long)N * 128;             // N*128
    int*   csr_src = (int*)(bufB + (long)N * 128);  // E
    int*   cnt     = csr_src + E;                   // N
    int*   rowptr  = cnt + N;                       // N+1
    int*   cursor  = rowptr + N + 1;                // N
    float* dinv    = (float*)(cursor + N);          // N
    int*   part    = (int*)(dinv + N);              // SCP
    float* z    = bufA;                             // N*64 (reuse)
    float* zout = bufA + (long)N * 64;              // N*64 (reuse)

    auto cdiv = [](long a, long b) { return (int)((a + b - 1) / b); };

    // ---- CSR build + normalization ----
    hipMemsetAsync(cnt, 0, (size_t)N * sizeof(int), stream);
    k_count <<<cdiv(E, 256), 256, 0, stream>>>(dst, cnt, E);
    k_scan_a<<<SCP / 256, 256, 0, stream>>>(cnt, part, N);
    k_scan_b<<<1, SCP, 0, stream>>>(part);
    k_scan_c<<<SCP / 256, 256, 0, stream>>>(cnt, part, rowptr, cursor, dinv, N);
    k_fillx <<<8 * 192, 256, 0, stream>>>(src, dst, cursor, csr_src, E, 8.0f / (float)N);

    // ---- layer 1: h = relu(agg(x @ W1) + b1) ----
    k_gemm<128><<<cdiv(N, 128), 256, 0, stream>>>(x, W1, dinv, bufA, N);
    k_gather<128, true><<<cdiv((long)N * 32, 256), 256, 0, stream>>>(
        rowptr, csr_src, dinv, bufA, b1, bufB, N);

    // ---- layer 2: z = agg(h @ W2) + b2 ----
    k_gemm<64><<<cdiv(N, 128), 256, 0, stream>>>(bufB, W2, dinv, z, N);
    k_gather<64, false><<<cdiv((long)N * 16, 256), 256, 0, stream>>>(
        rowptr, csr_src, dinv, z, b2, zout, N);

    // ---- decode ----
    k_decode<<<cdiv((long)L * 16, 256), 256, 0, stream>>>(la, lb, zout, out, L);
}

// Round 8
// 496.925 us; speedup vs baseline: 1.6440x; 1.0409x over previous
//
#include <hip/hip_runtime.h>

// ================= degree + per-edge rank =================

__global__ void k_count(const int* __restrict__ dst, int* __restrict__ cnt,
                        unsigned short* __restrict__ rank, int e) {
    int i = blockIdx.x * blockDim.x + threadIdx.x;
    if (i < e) {
        int r = atomicAdd(&cnt[dst[i]], 1);
        rank[i] = (unsigned short)r;
    }
}

// ---- 3-phase scan over cnt -> rowptr (+ dinv fused) ----
#define SCP 1024

__global__ void k_scan_a(const int* __restrict__ cnt, int* __restrict__ part, int n) {
    int p = blockIdx.x * blockDim.x + threadIdx.x;
    if (p >= SCP) return;
    int chunk = (n + SCP - 1) / SCP;
    int b = p * chunk, e = min(b + chunk, n), s = 0;
    for (int i = b; i < e; ++i) s += cnt[i];
    part[p] = s;
}

__global__ void k_scan_b(int* __restrict__ part) {   // 1 block, 1024 threads
    __shared__ int sm[SCP];
    int t = threadIdx.x;
    sm[t] = part[t];
    __syncthreads();
    for (int off = 1; off < SCP; off <<= 1) {
        int v = (t >= off) ? sm[t - off] : 0;
        __syncthreads();
        sm[t] += v;
        __syncthreads();
    }
    part[t] = t ? sm[t - 1] : 0;   // exclusive
}

__global__ void k_scan_c(const int* __restrict__ cnt, const int* __restrict__ part,
                         int* __restrict__ rowptr, float* __restrict__ dinv, int n) {
    int p = blockIdx.x * blockDim.x + threadIdx.x;
    if (p >= SCP) return;
    int chunk = (n + SCP - 1) / SCP;
    int b = p * chunk, e = min(b + chunk, n);
    int run = part[p];
    for (int i = b; i < e; ++i) {
        rowptr[i] = run;
        dinv[i] = rsqrtf((float)(cnt[i] + 1));   // +1 self-loop
        run += cnt[i];
    }
    if (p == SCP - 1) rowptr[n] = run;
}

// ---- XCD-partitioned CSR fill, atomic-free (rank precomputed in k_count) ----
__global__ void k_fillx(const int* __restrict__ src, const int* __restrict__ dstv,
                        const unsigned short* __restrict__ rank,
                        const int* __restrict__ rowptr, int* __restrict__ csr_src,
                        int e, float scale) {
    int r = blockIdx.x & 7;
    int g = blockIdx.x >> 3;
    int G = gridDim.x >> 3;
    int chunk = (e + G - 1) / G;
    int beg = g * chunk, end = min(beg + chunk, e);
    for (int i = beg + threadIdx.x; i < end; i += blockDim.x) {
        int d = dstv[i];
        if ((int)((float)d * scale) == r) {
            int pos = rowptr[d] + (int)rank[i];
            __builtin_nontemporal_store(src[i], &csr_src[pos]);
        }
    }
}

// ================= GEMM: C[row] = dinv[row] * (A[row] @ W) =================
// BM=128 rows/block, BK=64 k-slab (2 slabs), 256 threads as 16x16, 8 x TN tile.
// Staging via global_load_lds (16B, direct-to-LDS). sA linear [row][64] with
// granule swizzle: 16B granule G of row r stored at G ^ ((r>>3)&7)  -> a-reads
// are 2-way (free); achieved by pre-swizzling the per-lane GLOBAL source addr.
// sW linear [k][COUT]: w-reads conflict-free unpadded (4 tc values/wave).

template<int COUT>
__global__ __launch_bounds__(256) void k_gemm(const float* __restrict__ A,
                                              const float* __restrict__ W,
                                              const float* __restrict__ dinv,
                                              float* __restrict__ C, int n) {
    const int BM = 128, BK = 64;
    const int TN = COUT / 16;                 // 8 (COUT=128) or 4 (COUT=64)
    __shared__ float sA[BM * BK];             // 32 KB
    __shared__ float sW[BK * COUT];           // 32 KB (COUT=128) / 16 KB

    int tid = threadIdx.x;
    int lane = tid & 63;
    int wv = tid >> 6;                        // wave 0..3
    int row0 = blockIdx.x * BM;
    int tr = tid & 15, tc = tid >> 4;
    int c0 = tc * TN;

    float acc[8][TN];
#pragma unroll
    for (int i = 0; i < 8; ++i)
#pragma unroll
        for (int j = 0; j < TN; ++j) acc[i][j] = 0.f;

    for (int slab = 0; slab < 2; ++slab) {
        if (slab) __syncthreads();            // protect LDS overwrite

        // ---- stage A slab: 32 KB = 32 wave-chunks of 1KB, 8 iters x 4 waves ----
#pragma unroll
        for (int it = 0; it < 8; ++it) {
            int chunk = it * 4 + wv;
            int L = chunk * 64 + lane;        // linear granule index in slab
            int row = L >> 4;                 // 16 granules (64 floats) per row
            int gp = L & 15;
            int gsrc = gp ^ ((row >> 3) & 7); // pre-swizzled source granule
            int grow = min(row0 + row, n - 1);
            const float* srcp = A + (long)grow * 128 + slab * 64 + gsrc * 4;
            float* dstp = sA + chunk * 256;   // wave-uniform LDS base (1KB chunk)
            __builtin_amdgcn_global_load_lds(
                (const __attribute__((address_space(1))) void*)srcp,
                (__attribute__((address_space(3))) void*)dstp, 16, 0, 0);
        }
        // ---- stage W slab: linear [k][COUT] ----
        const int WCH = BK * COUT * 4 / 1024; // chunks: 32 (COUT=128) / 16
#pragma unroll
        for (int it = 0; it < WCH / 4; ++it) {
            int chunk = it * 4 + wv;
            int L = chunk * 64 + lane;
            int k = L / (COUT / 4);
            int gp = L % (COUT / 4);
            const float* srcp = W + (long)(slab * 64 + k) * COUT + gp * 4;
            float* dstp = sW + chunk * 256;
            __builtin_amdgcn_global_load_lds(
                (const __attribute__((address_space(1))) void*)srcp,
                (__attribute__((address_space(3))) void*)dstp, 16, 0, 0);
        }
        __syncthreads();                      // vmcnt drained by barrier

        // ---- compute 64 k (16 chunks of 4) ----
#pragma unroll
        for (int k4 = 0; k4 < 16; ++k4) {
            int slot = k4 ^ (tr & 7);         // un-swizzle ((r>>3)&7 == tr for our rows)
            float4 a4[8];
#pragma unroll
            for (int i = 0; i < 8; ++i)
                a4[i] = *reinterpret_cast<const float4*>(&sA[(tr * 8 + i) * 64 + slot * 4]);
#pragma unroll
            for (int kk = 0; kk < 4; ++kk) {
                float w[TN];
#pragma unroll
                for (int j = 0; j < TN; j += 4)
                    *reinterpret_cast<float4*>(&w[j]) =
                        *reinterpret_cast<const float4*>(&sW[(k4 * 4 + kk) * COUT + c0 + j]);
#pragma unroll
                for (int i = 0; i < 8; ++i) {
                    float av = (kk == 0) ? a4[i].x : (kk == 1) ? a4[i].y
                             : (kk == 2) ? a4[i].z : a4[i].w;
#pragma unroll
                    for (int j = 0; j < TN; ++j)
                        acc[i][j] = fmaf(av, w[j], acc[i][j]);
                }
            }
        }
    }

    // ---- epilogue: dinv scale + store ----
#pragma unroll
    for (int i = 0; i < 8; ++i) {
        int row = row0 + tr * 8 + i;
        if (row < n) {
            float dv = dinv[row];
#pragma unroll
            for (int j = 0; j < TN; ++j) acc[i][j] *= dv;
#pragma unroll
            for (int j = 0; j < TN; j += 4)
                *reinterpret_cast<float4*>(C + (long)row * COUT + c0 + j) =
                    *reinterpret_cast<float4*>(&acc[i][j]);
        }
    }
}

// ================= pull aggregation =================
// out[d] = act( dinv[d] * ( ht[d] + sum_{s in N(d)} ht[s] ) + bias ),  ht pre-scaled by dinv.

template<int C, bool RELU>
__global__ void k_gather(const int* __restrict__ rowptr, const int* __restrict__ csr_src,
                         const float* __restrict__ dinv, const float* __restrict__ h,
                         const float* __restrict__ bias, float* __restrict__ out, int n) {
    const int TPN = C / 4;
    int t = blockIdx.x * blockDim.x + threadIdx.x;
    int node = t / TPN;
    if (node >= n) return;
    int c = (t % TPN) * 4;

    const float4* h4 = reinterpret_cast<const float4*>(h);
    float4 acc = h4[((long)node * C + c) >> 2];   // self-loop term (already dinv-scaled)

    int beg = rowptr[node], end = rowptr[node + 1];
    int e = beg;
    for (; e + 8 <= end; e += 8) {
        int s[8];
#pragma unroll
        for (int q = 0; q < 8; ++q) s[q] = csr_src[e + q];
        float4 u[8];
#pragma unroll
        for (int q = 0; q < 8; ++q) u[q] = h4[((long)s[q] * C + c) >> 2];
        float sx0 = (u[0].x + u[1].x) + (u[2].x + u[3].x);
        float sx1 = (u[4].x + u[5].x) + (u[6].x + u[7].x);
        float sy0 = (u[0].y + u[1].y) + (u[2].y + u[3].y);
        float sy1 = (u[4].y + u[5].y) + (u[6].y + u[7].y);
        float sz0 = (u[0].z + u[1].z) + (u[2].z + u[3].z);
        float sz1 = (u[4].z + u[5].z) + (u[6].z + u[7].z);
        float sw0 = (u[0].w + u[1].w) + (u[2].w + u[3].w);
        float sw1 = (u[4].w + u[5].w) + (u[6].w + u[7].w);
        acc.x += sx0 + sx1; acc.y += sy0 + sy1;
        acc.z += sz0 + sz1; acc.w += sw0 + sw1;
    }
    for (; e < end; ++e) {
        int s = csr_src[e];
        float4 u = h4[((long)s * C + c) >> 2];
        acc.x += u.x; acc.y += u.y; acc.z += u.z; acc.w += u.w;
    }
    float dd = dinv[node];
    float4 b4 = *reinterpret_cast<const float4*>(bias + c);
    acc.x = fmaf(acc.x, dd, b4.x);
    acc.y = fmaf(acc.y, dd, b4.y);
    acc.z = fmaf(acc.z, dd, b4.z);
    acc.w = fmaf(acc.w, dd, b4.w);
    if (RELU) {
        acc.x = fmaxf(acc.x, 0.f); acc.y = fmaxf(acc.y, 0.f);
        acc.z = fmaxf(acc.z, 0.f); acc.w = fmaxf(acc.w, 0.f);
    }
    reinterpret_cast<float4*>(out)[((long)node * C + c) >> 2] = acc;
}

// ================= decode =================

__global__ void k_decode(const int* __restrict__ ia, const int* __restrict__ ib,
                         const float* __restrict__ z, float* __restrict__ out, int m) {
    int t = blockIdx.x * blockDim.x + threadIdx.x;
    int k = t / 16;
    if (k >= m) return;
    int c = (t & 15) * 4;
    int a = ia[k], b = ib[k];
    float4 va = *reinterpret_cast<const float4*>(z + (long)a * 64 + c);
    float4 vb = *reinterpret_cast<const float4*>(z + (long)b * 64 + c);
    float dot = va.x * vb.x + va.y * vb.y + va.z * vb.z + va.w * vb.w;
    dot += __shfl_xor(dot, 8);
    dot += __shfl_xor(dot, 4);
    dot += __shfl_xor(dot, 2);
    dot += __shfl_xor(dot, 1);
    if ((t & 15) == 0) out[k] = dot;
}

// ================= launcher =================

extern "C" void kernel_launch(void* const* d_in, const int* in_sizes, int n_in,
                              void* d_out, int out_size, void* d_ws, size_t ws_size,
                              hipStream_t stream) {
    const float* x  = (const float*)d_in[0];
    const int*   ei = (const int*)d_in[1];
    const int*   el = (const int*)d_in[2];
    const float* W1 = (const float*)d_in[3];
    const float* b1 = (const float*)d_in[4];
    const float* W2 = (const float*)d_in[5];
    const float* b2 = (const float*)d_in[6];
    float* out = (float*)d_out;

    const int N = in_sizes[0] / 128;
    const int E = in_sizes[1] / 2;
    const int L = out_size;

    const int* src = ei;
    const int* dst = ei + E;
    const int* la  = el;
    const int* lb  = el + L;

    // ---- workspace layout ----
    float* bufA = (float*)d_ws;                     // N*128 (rank overlays during CSR build)
    float* bufB = bufA + (long)N * 128;             // N*128
    int*   csr_src = (int*)(bufB + (long)N * 128);  // E
    int*   cnt     = csr_src + E;                   // N
    int*   rowptr  = cnt + N;                       // N+1
    float* dinv    = (float*)(rowptr + N + 1);      // N
    int*   part    = (int*)(dinv + N);              // SCP
    unsigned short* rank = (unsigned short*)bufA;   // E ushort (dies before gemm128)
    float* z    = bufA;                             // N*64 (reuse)
    float* zout = bufA + (long)N * 64;              // N*64 (reuse)

    auto cdiv = [](long a, long b) { return (int)((a + b - 1) / b); };

    // ---- CSR build + normalization ----
    hipMemsetAsync(cnt, 0, (size_t)N * sizeof(int), stream);
    k_count <<<cdiv(E, 256), 256, 0, stream>>>(dst, cnt, rank, E);
    k_scan_a<<<SCP / 256, 256, 0, stream>>>(cnt, part, N);
    k_scan_b<<<1, SCP, 0, stream>>>(part);
    k_scan_c<<<SCP / 256, 256, 0, stream>>>(cnt, part, rowptr, dinv, N);
    k_fillx <<<8 * 192, 256, 0, stream>>>(src, dst, rank, rowptr, csr_src, E, 8.0f / (float)N);

    // ---- layer 1: h = relu(agg(x @ W1) + b1) ----
    k_gemm<128><<<cdiv(N, 128), 256, 0, stream>>>(x, W1, dinv, bufA, N);
    k_gather<128, true><<<cdiv((long)N * 32, 256), 256, 0, stream>>>(
        rowptr, csr_src, dinv, bufA, b1, bufB, N);

    // ---- layer 2: z = agg(h @ W2) + b2 ----
    k_gemm<64><<<cdiv(N, 128), 256, 0, stream>>>(bufB, W2, dinv, z, N);
    k_gather<64, false><<<cdiv((long)N * 16, 256), 256, 0, stream>>>(
        rowptr, csr_src, dinv, z, b2, zout, N);

    // ---- decode ----
    k_decode<<<cdiv((long)L * 16, 256), 256, 0, stream>>>(la, lb, zout, out, L);
}

// Round 9
// 464.459 us; speedup vs baseline: 1.7590x; 1.0699x over previous
//
#include <hip/hip_runtime.h>

// ================= degree + packed (dst,rank) =================

__global__ void k_count(const int* __restrict__ dst, int* __restrict__ cnt,
                        unsigned int* __restrict__ pack, int e) {
    int i = blockIdx.x * blockDim.x + threadIdx.x;
    if (i < e) {
        int d = dst[i];
        int r = atomicAdd(&cnt[d], 1);
        pack[i] = ((unsigned int)d << 14) | (unsigned int)r;   // deg < 2^14 guaranteed
    }
}

// ---- 3-phase scan over cnt -> rowptr (+ dinv fused) ----
#define SCP 1024

__global__ void k_scan_a(const int* __restrict__ cnt, int* __restrict__ part, int n) {
    int p = blockIdx.x * blockDim.x + threadIdx.x;
    if (p >= SCP) return;
    int chunk = (n + SCP - 1) / SCP;
    int b = p * chunk, e = min(b + chunk, n), s = 0;
    for (int i = b; i < e; ++i) s += cnt[i];
    part[p] = s;
}

__global__ void k_scan_b(int* __restrict__ part) {   // 1 block, 1024 threads
    __shared__ int sm[SCP];
    int t = threadIdx.x;
    sm[t] = part[t];
    __syncthreads();
    for (int off = 1; off < SCP; off <<= 1) {
        int v = (t >= off) ? sm[t - off] : 0;
        __syncthreads();
        sm[t] += v;
        __syncthreads();
    }
    part[t] = t ? sm[t - 1] : 0;   // exclusive
}

__global__ void k_scan_c(const int* __restrict__ cnt, const int* __restrict__ part,
                         int* __restrict__ rowptr, float* __restrict__ dinv, int n) {
    int p = blockIdx.x * blockDim.x + threadIdx.x;
    if (p >= SCP) return;
    int chunk = (n + SCP - 1) / SCP;
    int b = p * chunk, e = min(b + chunk, n);
    int run = part[p];
    for (int i = b; i < e; ++i) {
        rowptr[i] = run;
        dinv[i] = rsqrtf((float)(cnt[i] + 1));   // +1 self-loop
        run += cnt[i];
    }
    if (p == SCP - 1) rowptr[n] = run;
}

// ---- XCD-partitioned CSR fill, atomic-free, single packed stream ----
__global__ void k_fillx(const int* __restrict__ src, const unsigned int* __restrict__ pack,
                        const int* __restrict__ rowptr, int* __restrict__ csr_src,
                        int e, float scale) {
    int r = blockIdx.x & 7;
    int g = blockIdx.x >> 3;
    int G = gridDim.x >> 3;
    int chunk = (e + G - 1) / G;
    int beg = g * chunk, end = min(beg + chunk, e);
    for (int i = beg + threadIdx.x; i < end; i += blockDim.x) {
        unsigned int p = pack[i];
        int d = (int)(p >> 14);
        if ((int)((float)d * scale) == r) {
            int pos = rowptr[d] + (int)(p & 0x3FFFu);
            __builtin_nontemporal_store(src[i], &csr_src[pos]);
        }
    }
}

// ================= GEMM: C[row] = dinv[row] * (A[row] @ W) =================
// BM=128 rows/block, BK=32 k-slab (4 slabs), 256 threads as 16x16, 8 x TN tile.
// global_load_lds(16B) staging; sA linear [row][32] with granule swizzle
// gsrc = gp ^ ((row>>3)&7) (pre-swizzled GLOBAL source, linear LDS dest);
// read back with slot = k4 ^ (tr&7) -> 2-way conflicts (free). sW linear:
// 16-lane groups read identical addresses (broadcast, conflict-free).
// LDS 32 KB (COUT=128) / 24 KB -> 5-6 blocks/CU for inter-block overlap.

template<int COUT>
__global__ __launch_bounds__(256) void k_gemm(const float* __restrict__ A,
                                              const float* __restrict__ W,
                                              const float* __restrict__ dinv,
                                              float* __restrict__ C, int n) {
    const int BM = 128, BK = 32;
    const int TN = COUT / 16;                 // 8 (COUT=128) or 4 (COUT=64)
    __shared__ float sA[BM * BK];             // 16 KB
    __shared__ float sW[BK * COUT];           // 16 KB / 8 KB

    int tid = threadIdx.x;
    int lane = tid & 63;
    int wv = tid >> 6;                        // wave 0..3
    int row0 = blockIdx.x * BM;
    int tr = tid & 15, tc = tid >> 4;
    int c0 = tc * TN;

    float acc[8][TN];
#pragma unroll
    for (int i = 0; i < 8; ++i)
#pragma unroll
        for (int j = 0; j < TN; ++j) acc[i][j] = 0.f;

    for (int slab = 0; slab < 4; ++slab) {
        if (slab) __syncthreads();            // protect LDS overwrite

        // ---- stage A slab: 16 KB = 16 chunks of 1KB, 4 iters x 4 waves ----
#pragma unroll
        for (int it = 0; it < 4; ++it) {
            int chunk = it * 4 + wv;
            int L = chunk * 64 + lane;        // linear granule index in slab
            int row = L >> 3;                 // 8 granules (32 floats) per row
            int gp = L & 7;
            int gsrc = gp ^ ((row >> 3) & 7); // pre-swizzled source granule
            int grow = min(row0 + row, n - 1);
            const float* srcp = A + (long)grow * 128 + slab * 32 + gsrc * 4;
            float* dstp = sA + chunk * 256;   // wave-uniform LDS base (1KB chunk)
            __builtin_amdgcn_global_load_lds(
                (const __attribute__((address_space(1))) void*)srcp,
                (__attribute__((address_space(3))) void*)dstp, 16, 0, 0);
        }
        // ---- stage W slab: linear [k][COUT] ----
        const int WCH = BK * COUT * 4 / 1024; // chunks: 16 (COUT=128) / 8
#pragma unroll
        for (int it = 0; it < WCH / 4; ++it) {
            int chunk = it * 4 + wv;
            int L = chunk * 64 + lane;
            int k = L / (COUT / 4);
            int gp = L % (COUT / 4);
            const float* srcp = W + (long)(slab * 32 + k) * COUT + gp * 4;
            float* dstp = sW + chunk * 256;
            __builtin_amdgcn_global_load_lds(
                (const __attribute__((address_space(1))) void*)srcp,
                (__attribute__((address_space(3))) void*)dstp, 16, 0, 0);
        }
        __syncthreads();                      // drains vmcnt

        // ---- compute 32 k (8 chunks of 4) ----
#pragma unroll
        for (int k4 = 0; k4 < 8; ++k4) {
            int slot = k4 ^ (tr & 7);         // un-swizzle
            float4 a4[8];
#pragma unroll
            for (int i = 0; i < 8; ++i)
                a4[i] = *reinterpret_cast<const float4*>(&sA[(tr * 8 + i) * 32 + slot * 4]);
#pragma unroll
            for (int kk = 0; kk < 4; ++kk) {
                float w[TN];
#pragma unroll
                for (int j = 0; j < TN; j += 4)
                    *reinterpret_cast<float4*>(&w[j]) =
                        *reinterpret_cast<const float4*>(&sW[(k4 * 4 + kk) * COUT + c0 + j]);
#pragma unroll
                for (int i = 0; i < 8; ++i) {
                    float av = (kk == 0) ? a4[i].x : (kk == 1) ? a4[i].y
                             : (kk == 2) ? a4[i].z : a4[i].w;
#pragma unroll
                    for (int j = 0; j < TN; ++j)
                        acc[i][j] = fmaf(av, w[j], acc[i][j]);
                }
            }
        }
    }

    // ---- epilogue: dinv scale + store ----
#pragma unroll
    for (int i = 0; i < 8; ++i) {
        int row = row0 + tr * 8 + i;
        if (row < n) {
            float dv = dinv[row];
#pragma unroll
            for (int j = 0; j < TN; ++j) acc[i][j] *= dv;
#pragma unroll
            for (int j = 0; j < TN; j += 4)
                *reinterpret_cast<float4*>(C + (long)row * COUT + c0 + j) =
                    *reinterpret_cast<float4*>(&acc[i][j]);
        }
    }
}

// ================= pull aggregation =================
// out[d] = act( dinv[d] * ( ht[d] + sum_{s in N(d)} ht[s] ) + bias ),  ht pre-scaled by dinv.

template<int C, bool RELU>
__global__ void k_gather(const int* __restrict__ rowptr, const int* __restrict__ csr_src,
                         const float* __restrict__ dinv, const float* __restrict__ h,
                         const float* __restrict__ bias, float* __restrict__ out, int n) {
    const int TPN = C / 4;
    int t = blockIdx.x * blockDim.x + threadIdx.x;
    int node = t / TPN;
    if (node >= n) return;
    int c = (t % TPN) * 4;

    const float4* h4 = reinterpret_cast<const float4*>(h);
    float4 acc = h4[((long)node * C + c) >> 2];   // self-loop term (already dinv-scaled)

    int beg = rowptr[node], end = rowptr[node + 1];
    int e = beg;
    for (; e + 8 <= end; e += 8) {
        int s[8];
#pragma unroll
        for (int q = 0; q < 8; ++q) s[q] = csr_src[e + q];
        float4 u[8];
#pragma unroll
        for (int q = 0; q < 8; ++q) u[q] = h4[((long)s[q] * C + c) >> 2];
        float sx0 = (u[0].x + u[1].x) + (u[2].x + u[3].x);
        float sx1 = (u[4].x + u[5].x) + (u[6].x + u[7].x);
        float sy0 = (u[0].y + u[1].y) + (u[2].y + u[3].y);
        float sy1 = (u[4].y + u[5].y) + (u[6].y + u[7].y);
        float sz0 = (u[0].z + u[1].z) + (u[2].z + u[3].z);
        float sz1 = (u[4].z + u[5].z) + (u[6].z + u[7].z);
        float sw0 = (u[0].w + u[1].w) + (u[2].w + u[3].w);
        float sw1 = (u[4].w + u[5].w) + (u[6].w + u[7].w);
        acc.x += sx0 + sx1; acc.y += sy0 + sy1;
        acc.z += sz0 + sz1; acc.w += sw0 + sw1;
    }
    for (; e < end; ++e) {
        int s = csr_src[e];
        float4 u = h4[((long)s * C + c) >> 2];
        acc.x += u.x; acc.y += u.y; acc.z += u.z; acc.w += u.w;
    }
    float dd = dinv[node];
    float4 b4 = *reinterpret_cast<const float4*>(bias + c);
    acc.x = fmaf(acc.x, dd, b4.x);
    acc.y = fmaf(acc.y, dd, b4.y);
    acc.z = fmaf(acc.z, dd, b4.z);
    acc.w = fmaf(acc.w, dd, b4.w);
    if (RELU) {
        acc.x = fmaxf(acc.x, 0.f); acc.y = fmaxf(acc.y, 0.f);
        acc.z = fmaxf(acc.z, 0.f); acc.w = fmaxf(acc.w, 0.f);
    }
    reinterpret_cast<float4*>(out)[((long)node * C + c) >> 2] = acc;
}

// ================= decode =================

__global__ void k_decode(const int* __restrict__ ia, const int* __restrict__ ib,
                         const float* __restrict__ z, float* __restrict__ out, int m) {
    int t = blockIdx.x * blockDim.x + threadIdx.x;
    int k = t / 16;
    if (k >= m) return;
    int c = (t & 15) * 4;
    int a = ia[k], b = ib[k];
    float4 va = *reinterpret_cast<const float4*>(z + (long)a * 64 + c);
    float4 vb = *reinterpret_cast<const float4*>(z + (long)b * 64 + c);
    float dot = va.x * vb.x + va.y * vb.y + va.z * vb.z + va.w * vb.w;
    dot += __shfl_xor(dot, 8);
    dot += __shfl_xor(dot, 4);
    dot += __shfl_xor(dot, 2);
    dot += __shfl_xor(dot, 1);
    if ((t & 15) == 0) out[k] = dot;
}

// ================= launcher =================

extern "C" void kernel_launch(void* const* d_in, const int* in_sizes, int n_in,
                              void* d_out, int out_size, void* d_ws, size_t ws_size,
                              hipStream_t stream) {
    const float* x  = (const float*)d_in[0];
    const int*   ei = (const int*)d_in[1];
    const int*   el = (const int*)d_in[2];
    const float* W1 = (const float*)d_in[3];
    const float* b1 = (const float*)d_in[4];
    const float* W2 = (const float*)d_in[5];
    const float* b2 = (const float*)d_in[6];
    float* out = (float*)d_out;

    const int N = in_sizes[0] / 128;
    const int E = in_sizes[1] / 2;
    const int L = out_size;

    const int* src = ei;
    const int* dst = ei + E;
    const int* la  = el;
    const int* lb  = el + L;

    // ---- workspace layout ----
    float* bufA = (float*)d_ws;                     // N*128 (pack overlays during CSR build)
    float* bufB = bufA + (long)N * 128;             // N*128
    int*   csr_src = (int*)(bufB + (long)N * 128);  // E
    int*   cnt     = csr_src + E;                   // N
    int*   rowptr  = cnt + N;                       // N+1
    float* dinv    = (float*)(rowptr + N + 1);      // N
    int*   part    = (int*)(dinv + N);              // SCP
    unsigned int* pack = (unsigned int*)bufA;       // E u32 (dies before gemm128)
    float* z    = bufA;                             // N*64 (reuse)
    float* zout = bufA + (long)N * 64;              // N*64 (reuse)

    auto cdiv = [](long a, long b) { return (int)((a + b - 1) / b); };

    // ---- CSR build + normalization ----
    hipMemsetAsync(cnt, 0, (size_t)N * sizeof(int), stream);
    k_count <<<cdiv(E, 256), 256, 0, stream>>>(dst, cnt, pack, E);
    k_scan_a<<<SCP / 256, 256, 0, stream>>>(cnt, part, N);
    k_scan_b<<<1, SCP, 0, stream>>>(part);
    k_scan_c<<<SCP / 256, 256, 0, stream>>>(cnt, part, rowptr, dinv, N);
    k_fillx <<<8 * 192, 256, 0, stream>>>(src, pack, rowptr, csr_src, E, 8.0f / (float)N);

    // ---- layer 1: h = relu(agg(x @ W1) + b1) ----
    k_gemm<128><<<cdiv(N, 128), 256, 0, stream>>>(x, W1, dinv, bufA, N);
    k_gather<128, true><<<cdiv((long)N * 32, 256), 256, 0, stream>>>(
        rowptr, csr_src, dinv, bufA, b1, bufB, N);

    // ---- layer 2: z = agg(h @ W2) + b2 ----
    k_gemm<64><<<cdiv(N, 128), 256, 0, stream>>>(bufB, W2, dinv, z, N);
    k_gather<64, false><<<cdiv((long)N * 16, 256), 256, 0, stream>>>(
        rowptr, csr_src, dinv, z, b2, zout, N);

    // ---- decode ----
    k_decode<<<cdiv((long)L * 16, 256), 256, 0, stream>>>(la, lb, zout, out, L);
}